// Round 9
// baseline (121.454 us; speedup 1.0000x reference)
//
#include <hip/hip_runtime.h>
#include <hip/hip_bf16.h>
#include <stdint.h>

#define BATCH 32
#define CIN   256
#define COUT  256
#define HW    3136   // 56*56
#define NPAD  3200   // pad HW to multiple of 128

#define AS1 __attribute__((address_space(1)))
#define AS3 __attribute__((address_space(3)))

typedef short bf16x8 __attribute__((ext_vector_type(8)));
typedef float f32x4  __attribute__((ext_vector_type(4)));

__device__ __forceinline__ unsigned short f2bf(float f) {
    unsigned u = __float_as_uint(f);
    u += 0x7fffu + ((u >> 16) & 1u);   // round-to-nearest-even
    return (unsigned short)(u >> 16);
}

// ---------------- K0: fold BN2 into pw weights; zero pwmax -----------------
__global__ __launch_bounds__(256) void prep_kernel(
        const float* __restrict__ pw_w, const float* __restrict__ pw_b,
        const float* __restrict__ g2, const float* __restrict__ be2,
        const float* __restrict__ mu2, const float* __restrict__ va2,
        unsigned short* __restrict__ Wp, float* __restrict__ b2,
        unsigned* __restrict__ pwmax) {
    int o = blockIdx.x;
    int t = threadIdx.x;
    float inv2 = g2[o] * rsqrtf(va2[o] + 1e-5f);
    Wp[o * CIN + t] = f2bf(pw_w[o * CIN + t] * inv2);
    if (t == 0) b2[o] = pw_b[o] * inv2 + be2[o] - mu2[o] * inv2;
    int idx = blockIdx.x * 256 + t;
    if (idx < BATCH * COUT) pwmax[idx] = 0u;
}

// ---------------- K1: depthwise 3x3 + BN1 + ReLU + SELF-CUT -> y bf16 -----
// (unchanged from R8)
__global__ __launch_bounds__(256) void dw_kernel(
        const float* __restrict__ x, const float* __restrict__ dww,
        const float* __restrict__ dwb,
        const float* __restrict__ g1, const float* __restrict__ be1,
        const float* __restrict__ mu1, const float* __restrict__ va1,
        unsigned short* __restrict__ y) {
    __shared__ float xs[4 * 3136];     // 50,176 B -> 3 blocks/CU
    int tid  = threadIdx.x;
    int lane = tid & 63, wid = tid >> 6;
    int plane = blockIdx.x * 4 + wid;  // 2048 blocks x 4 planes
    int c = plane & 255;

    const float* xp = x + (size_t)plane * HW;
    float* xw = xs + wid * 3136;

#pragma unroll
    for (int i = 0; i < 12; ++i)
        __builtin_amdgcn_global_load_lds(
            (const AS1 void*)(xp + i * 256 + lane * 4),
            (AS3 void*)(xw + i * 256), 16, 0, 0);
    __builtin_amdgcn_global_load_lds(
        (const AS1 void*)(xp + 3072 + lane),
        (AS3 void*)(xw + 3072), 4, 0, 0);

    float w00 = dww[c*9+0], w01 = dww[c*9+1], w02 = dww[c*9+2];
    float w10 = dww[c*9+3], w11 = dww[c*9+4], w12 = dww[c*9+5];
    float w20 = dww[c*9+6], w21 = dww[c*9+7], w22 = dww[c*9+8];
    float inv = g1[c] * rsqrtf(va1[c] + 1e-5f);
    float b0  = dwb[c] * inv + (be1[c] - mu1[c] * inv);

    int  col    = lane < 56 ? lane : 55;
    bool active = lane < 56;
    if (lane == 0)  { w00 = 0.f; w10 = 0.f; w20 = 0.f; }
    if (lane >= 55) { w02 = 0.f; w12 = 0.f; w22 = 0.f; }
    int il = (lane == 0) ? 0 : col - 1;
    int ir = (col == 55) ? 55 : col + 1;

    asm volatile("s_waitcnt vmcnt(0)" ::: "memory");
    __builtin_amdgcn_sched_barrier(0);

    const float* xb = xw;
    unsigned short* yp = y + (size_t)plane * NPAD + col;

    float A = 0.f;
    float Bv = 0.f;
    float lmax = 0.f;
#pragma unroll
    for (int q = 0; q < 56; q += 2) {
        float l0 = xb[q*56 + il],      c0 = xb[q*56 + col],      r0 = xb[q*56 + ir];
        float l1 = xb[(q+1)*56 + il],  c1 = xb[(q+1)*56 + col],  r1 = xb[(q+1)*56 + ir];
        if (q > 0) {
            float o0 = fmaf(l0, w20, fmaf(c0, w21, fmaf(r0, w22, A)));
            float v = fmaxf(fmaf(o0, inv, b0), 0.f);
            if (active) { lmax = fmaxf(lmax, v); yp[(q-1)*56] = f2bf(v); }
        }
        {
            float o1 = fmaf(l0, w10, fmaf(c0, w11, fmaf(r0, w12,
                       fmaf(l1, w20, fmaf(c1, w21, fmaf(r1, w22, Bv))))));
            float v = fmaxf(fmaf(o1, inv, b0), 0.f);
            if (active) { lmax = fmaxf(lmax, v); yp[q*56] = f2bf(v); }
        }
        float top0 = fmaf(l0, w00, fmaf(c0, w01, r0 * w02));
        A  = fmaf(l1, w10, fmaf(c1, w11, fmaf(r1, w12, top0)));
        Bv = fmaf(l1, w00, fmaf(c1, w01, r1 * w02));
    }
    {
        float v = fmaxf(fmaf(A, inv, b0), 0.f);
        if (active) { lmax = fmaxf(lmax, v); yp[55*56] = f2bf(v); }
    }
    for (int off = 32; off >= 1; off >>= 1)
        lmax = fmaxf(lmax, __shfl_xor(lmax, off, 64));
    if (lane < 8) *(uint4*)(y + (size_t)plane * NPAD + HW + lane * 8)
        = make_uint4(0, 0, 0, 0);
    if (lmax < 4.0f) {
        asm volatile("s_waitcnt vmcnt(0)" ::: "memory");
        unsigned short* yp0 = y + (size_t)plane * NPAD;
#pragma unroll
        for (int it = 0; it < 7; ++it) {
            int idx = it * 64 + lane;
            if (idx < 392) *(uint4*)(yp0 + idx * 8) = make_uint4(0, 0, 0, 0);
        }
    }
}

// ---------------- K2: pointwise GEMM, desynchronized waves -----------------
// BM=64, BN=128 (4 waves x 64o x 32n), K=256 in 4 steps of 64.
// A: 32KB LDS-resident (one barrier total). B: wave-private 4KB, VALU
// pack-transpose, 1-step reg prefetch. Steady-state loop: NO barriers.
__global__ __launch_bounds__(256, 3) void pw_kernel(
        const unsigned short* __restrict__ y, const unsigned short* __restrict__ Wp,
        const float* __restrict__ b2, float* __restrict__ z,
        unsigned* __restrict__ pwmax) {
    __shared__ __align__(16) char lds[32768 + 16384];  // A 32KB | B 4 x 4KB
    char* Al = lds;

    int bid0 = blockIdx.x;                  // 3200 = 8 * 400
    int bid  = (bid0 & 7) * 400 + (bid0 >> 3);   // XCD-contig (bijective)
    int nt   = bid % 25;
    int rest = bid / 25;
    int ot   = rest & 3;
    int b    = rest >> 2;
    int o0 = ot * 64, n0 = nt * 128;

    int tid = threadIdx.x, lane = tid & 63, wid = tid >> 6;
    char* Bw = lds + 32768 + wid * 4096;    // wave-private B region
    int wn = wid * 32;
    int l15 = lane & 15, l4 = lane >> 4;

    const unsigned short* yb = y + (size_t)b * CIN * NPAD;

    // ---- A DMA: 8 issues, linear dest (base + lane*16), pre-swizzled src --
#pragma unroll
    for (int i = 0; i < 8; ++i) {
        int s = i * 256 + tid;
        int m = s >> 5, cch = s & 31, dch = cch ^ (m & 7);
        __builtin_amdgcn_global_load_lds(
            (const AS1 void*)(Wp + (size_t)(o0 + m) * CIN + dch * 8),
            (AS3 void*)(Al + i * 4096 + wid * 1024), 16, 0, 0);
    }

    // B geometry: 2 units/lane; unit i: q = i*8 + (lane>>3), nq = lane&7
    int l3 = lane & 7, q3 = lane >> 3;
    const unsigned short* bbase = yb + n0 + wn + l3 * 4 + (size_t)(q3 * 4) * NPAD;

    uint2 praw[2][4];
#define LOADB(kk) { _Pragma("unroll") for (int i = 0; i < 2; ++i)             \
                    _Pragma("unroll") for (int r = 0; r < 4; ++r)             \
                      praw[i][r] = *(const uint2*)(bbase +                    \
                          ((size_t)(kk) * 64 + i * 32 + r) * NPAD); }

#define PACKB() { _Pragma("unroll") for (int i = 0; i < 2; ++i) {             \
        int q = i * 8 + q3;                                                   \
        uint2 r0 = praw[i][0], r1 = praw[i][1], r2 = praw[i][2], r3 = praw[i][3]; \
        _Pragma("unroll") for (int i2 = 0; i2 < 4; ++i2) {                    \
            unsigned x0 = (i2 & 2) ? r0.y : r0.x;                             \
            unsigned x1 = (i2 & 2) ? r1.y : r1.x;                             \
            unsigned x2 = (i2 & 2) ? r2.y : r2.x;                             \
            unsigned x3 = (i2 & 2) ? r3.y : r3.x;                             \
            if (i2 & 1) { x0 >>= 16; x2 >>= 16; }                             \
            else        { x0 &= 0xffffu; x2 &= 0xffffu; }                     \
            unsigned px = (i2 & 1) ? (x0 | (x1 & 0xffff0000u)) : (x0 | (x1 << 16)); \
            unsigned py = (i2 & 1) ? (x2 | (x3 & 0xffff0000u)) : (x2 | (x3 << 16)); \
            int nloc = l3 * 4 + i2;                                           \
            int sb = nloc * 128 + (((q >> 1) ^ ((nloc >> 2) & 7)) << 4) + ((q & 1) << 3); \
            *(uint2*)(Bw + sb) = make_uint2(px, py);                          \
        } } }

#define LGKM0 { asm volatile("s_waitcnt lgkmcnt(0)" ::: "memory");            \
                __builtin_amdgcn_sched_barrier(0); }

    f32x4 acc[4][2];
#pragma unroll
    for (int mf = 0; mf < 4; ++mf)
#pragma unroll
        for (int nf = 0; nf < 2; ++nf) acc[mf][nf] = {0.f, 0.f, 0.f, 0.f};

#define STEP(kk) { _Pragma("unroll") for (int h = 0; h < 2; ++h) {            \
        bf16x8 afr[4], bfr[2];                                                \
        int cc = (kk) * 8 + h * 4 + l4;                                       \
        _Pragma("unroll") for (int mf = 0; mf < 4; ++mf) {                    \
            int m = mf * 16 + l15;                                            \
            afr[mf] = *(const bf16x8*)(Al + m * 512 + ((cc ^ (m & 7)) << 4)); } \
        int cb = h * 4 + l4;                                                  \
        _Pragma("unroll") for (int nf = 0; nf < 2; ++nf) {                    \
            int nloc = nf * 16 + l15;                                         \
            bfr[nf] = *(const bf16x8*)(Bw + nloc * 128 + ((cb ^ ((nloc >> 2) & 7)) << 4)); } \
        _Pragma("unroll") for (int mf = 0; mf < 4; ++mf)                      \
            _Pragma("unroll") for (int nf = 0; nf < 2; ++nf)                  \
                acc[mf][nf] = __builtin_amdgcn_mfma_f32_16x16x32_bf16(        \
                    afr[mf], bfr[nf], acc[mf][nf], 0, 0, 0); } }

    // ---- prologue ----
    LOADB(0);                                       // 8 loads (after 8 DMA)
    asm volatile("s_waitcnt vmcnt(8)" ::: "memory"); // own A-DMA done
    __builtin_amdgcn_sched_barrier(0);
    __builtin_amdgcn_s_barrier();                   // A visible to all waves
    __builtin_amdgcn_sched_barrier(0);
    PACKB();                                        // B0 -> LDS
    LGKM0;
    LOADB(1);

    // ---- steady state: no barriers, waves free-run ----
    STEP(0);
    PACKB(); LGKM0; LOADB(2);
    STEP(1);
    PACKB(); LGKM0; LOADB(3);
    STEP(2);
    PACKB(); LGKM0;
    STEP(3);

#undef LOADB
#undef PACKB
#undef STEP

    // ---- epilogue: bias + relu + store + row max (atomic) ----
    float* zb = z + (size_t)b * COUT * HW;
#pragma unroll
    for (int mf = 0; mf < 4; ++mf) {
        int obase = o0 + mf * 16 + l4 * 4;
        float bb0 = b2[obase + 0], bb1 = b2[obase + 1];
        float bb2v = b2[obase + 2], bb3 = b2[obase + 3];
        float rmax[4] = {0.f, 0.f, 0.f, 0.f};
#pragma unroll
        for (int nf = 0; nf < 2; ++nf) {
            int n = n0 + wn + nf * 16 + l15;
            bool valid = (n < HW);
            float v0 = fmaxf(acc[mf][nf][0] + bb0, 0.f);
            float v1 = fmaxf(acc[mf][nf][1] + bb1, 0.f);
            float v2 = fmaxf(acc[mf][nf][2] + bb2v, 0.f);
            float v3 = fmaxf(acc[mf][nf][3] + bb3, 0.f);
            if (valid) {
                zb[(size_t)(obase + 0) * HW + n] = v0;
                zb[(size_t)(obase + 1) * HW + n] = v1;
                zb[(size_t)(obase + 2) * HW + n] = v2;
                zb[(size_t)(obase + 3) * HW + n] = v3;
                rmax[0] = fmaxf(rmax[0], v0);
                rmax[1] = fmaxf(rmax[1], v1);
                rmax[2] = fmaxf(rmax[2], v2);
                rmax[3] = fmaxf(rmax[3], v3);
            }
        }
#pragma unroll
        for (int r = 0; r < 4; ++r) {
            float v = rmax[r];
            v = fmaxf(v, __shfl_xor(v, 1, 64));
            v = fmaxf(v, __shfl_xor(v, 2, 64));
            v = fmaxf(v, __shfl_xor(v, 4, 64));
            v = fmaxf(v, __shfl_xor(v, 8, 64));
            if (l15 == 0)
                atomicMax(&pwmax[b * COUT + obase + r], __float_as_uint(v));
        }
    }
}

// ---------------- K3: apply pointwise cut ---------------------------------
__global__ __launch_bounds__(256) void cut_kernel(const unsigned* __restrict__ pwmax,
                                                  float* __restrict__ z) {
    int base = blockIdx.x * 8;
#pragma unroll
    for (int j = 0; j < 8; ++j) {
        int bo = base + j;
        if (__uint_as_float(pwmax[bo]) >= 1e-3f) continue;
        float4* zp = (float4*)(z + (size_t)bo * HW);
        for (int i = threadIdx.x; i < HW / 4; i += 256)
            zp[i] = make_float4(0.f, 0.f, 0.f, 0.f);
    }
}

extern "C" void kernel_launch(void* const* d_in, const int* in_sizes, int n_in,
                              void* d_out, int out_size, void* d_ws, size_t ws_size,
                              hipStream_t stream) {
    const float* x   = (const float*)d_in[0];
    const float* dww = (const float*)d_in[1];
    const float* dwb = (const float*)d_in[2];
    const float* g1  = (const float*)d_in[3];
    const float* be1 = (const float*)d_in[4];
    const float* mu1 = (const float*)d_in[5];
    const float* va1 = (const float*)d_in[6];
    const float* pww = (const float*)d_in[7];
    const float* pwb = (const float*)d_in[8];
    const float* g2  = (const float*)d_in[9];
    const float* be2 = (const float*)d_in[10];
    const float* mu2 = (const float*)d_in[11];
    const float* va2 = (const float*)d_in[12];
    float* z = (float*)d_out;

    char* ws = (char*)d_ws;
    const size_t Y_BYTES = (size_t)BATCH * CIN * NPAD * 2;  // 52,428,800
    unsigned short* y  = (unsigned short*)ws;
    unsigned short* Wp = (unsigned short*)(ws + Y_BYTES);
    float* b2          = (float*)(ws + Y_BYTES + 131072);
    unsigned* pwmax    = (unsigned*)(ws + Y_BYTES + 131072 + 1024);

    prep_kernel<<<256, 256, 0, stream>>>(pww, pwb, g2, be2, mu2, va2, Wp, b2, pwmax);
    dw_kernel<<<2048, 256, 0, stream>>>(x, dww, dwb, g1, be1, mu1, va1, y);
    pw_kernel<<<3200, 256, 0, stream>>>(y, Wp, b2, z, pwmax);
    cut_kernel<<<BATCH * COUT / 8, 256, 0, stream>>>(pwmax, z);
}